// Round 8
// baseline (616.760 us; speedup 1.0000x reference)
//
#include <hip/hip_runtime.h>

// ---------------- constants ----------------
#define Bn 4
#define Tn 2048
#define Cn 1024
#define Hn 16
#define Dn 64
#define Mr (Bn*Tn)          // 8192 rows

typedef _Float16 half8 __attribute__((ext_vector_type(8)));
typedef _Float16 half4v __attribute__((ext_vector_type(4)));
typedef _Float16 half2v __attribute__((ext_vector_type(2)));
typedef float f32x4 __attribute__((ext_vector_type(4)));
typedef unsigned u32x4 __attribute__((ext_vector_type(4)));

__device__ __forceinline__ void g2l16(const void* g, void* l) {
  __builtin_amdgcn_global_load_lds((__attribute__((address_space(1))) void*)g,
                                   (__attribute__((address_space(3))) void*)l, 16, 0, 0);
}

#define SB  __builtin_amdgcn_sched_barrier(0)
#define BAR __builtin_amdgcn_s_barrier()
#define VMW8 asm volatile("s_waitcnt vmcnt(8)" ::: "memory")
#define VMW6 asm volatile("s_waitcnt vmcnt(6)" ::: "memory")
#define VMW4 asm volatile("s_waitcnt vmcnt(4)" ::: "memory")
#define VMW3 asm volatile("s_waitcnt vmcnt(3)" ::: "memory")
#define VMW0 asm volatile("s_waitcnt vmcnt(0)" ::: "memory")

// ---------------- transpose f32 -> f16 (B^T weight prep) ----------------
__global__ __launch_bounds__(256) void transpose_f32_f16(const float* __restrict__ in,
                                                         _Float16* __restrict__ out,
                                                         int R, int C) {
  __shared__ float tile[32][33];
  const size_t zoff = (size_t)blockIdx.z * R * C;
  in += zoff; out += zoff;
  const int c0 = blockIdx.x * 32, r0 = blockIdx.y * 32;
  const int tx = threadIdx.x, ty = threadIdx.y;
#pragma unroll
  for (int i = 0; i < 4; ++i)
    tile[ty + i*8][tx] = in[(size_t)(r0 + ty + i*8) * C + c0 + tx];
  __syncthreads();
#pragma unroll
  for (int i = 0; i < 4; ++i)
    out[(size_t)(c0 + ty + i*8) * R + r0 + tx] = (_Float16)tile[tx][ty + i*8];
}

// ---------------- LayerNorm row kernel: f32 in -> f16 out ----------------
__global__ __launch_bounds__(256) void ln_row(const float* __restrict__ x,
                                              const float* __restrict__ g,
                                              const float* __restrict__ bta,
                                              _Float16* __restrict__ out) {
  const int row = blockIdx.x;
  const float4 v = ((const float4*)(x + (size_t)row * Cn))[threadIdx.x];
  float s  = v.x + v.y + v.z + v.w;
  float ss = v.x*v.x + v.y*v.y + v.z*v.z + v.w*v.w;
#pragma unroll
  for (int m = 1; m < 64; m <<= 1) { s += __shfl_xor(s, m); ss += __shfl_xor(ss, m); }
  __shared__ float red[8];
  const int wave = threadIdx.x >> 6, lane = threadIdx.x & 63;
  if (lane == 0) { red[wave] = s; red[4 + wave] = ss; }
  __syncthreads();
  s  = red[0] + red[1] + red[2] + red[3];
  ss = red[4] + red[5] + red[6] + red[7];
  const float mean = s * (1.0f/Cn);
  const float var  = ss * (1.0f/Cn) - mean*mean;
  const float rstd = rsqrtf(var + 1e-6f);
  const int c = threadIdx.x * 4;
  const float4 gg = ((const float4*)g)[threadIdx.x];
  const float4 bb = ((const float4*)bta)[threadIdx.x];
  half4v o;
  o[0] = (_Float16)((v.x - mean) * rstd * gg.x + bb.x);
  o[1] = (_Float16)((v.y - mean) * rstd * gg.y + bb.y);
  o[2] = (_Float16)((v.z - mean) * rstd * gg.z + bb.z);
  o[3] = (_Float16)((v.w - mean) * rstd * gg.w + bb.w);
  *((half4v*)(out + (size_t)row * Cn + c)) = o;
}

// ---------------- GEMM v3: 8-phase schedule, BM=256, BK=64, 8 waves ----------------
enum { EPI_QKV = 0, EPI_PROJ = 2, EPI_FF1 = 3, EPI_FF2 = 4 };

template<int BN, int EPI>
__global__ __launch_bounds__(512, 2) void gemm8p(const _Float16* __restrict__ A,
                                                 const _Float16* __restrict__ Bt,
                                                 void* __restrict__ outp,
                                                 void* __restrict__ out2,   // QKV: k
                                                 void* __restrict__ out3,   // QKV: vt
                                                 const float* __restrict__ bias,
                                                 const float* __restrict__ resid,
                                                 int M, int N, int K, int nxg) {
  constexpr int NF = BN/64;               // N-frags per wave (4 or 2)
  constexpr int BSLOT = BN*32;            // f16 per B slot
  __shared__ __align__(16) _Float16 Ar[4*256*32];
  __shared__ __align__(16) _Float16 Br[4*BSLOT];

  const int tid = threadIdx.x, wave = tid >> 6, lane = tid & 63;
  const int lr = lane & 15, lg = lane >> 4;
  const int sL = (lr & 3) ^ ((lr >> 2) & 3);
  const int laneoff = lr*32 + ((lg ^ sL) * 8);     // f16 offset within a slot

  // bijective XCD swizzle (gridDim.x % 8 == 0 for all our launches)
  int lin = blockIdx.x;
  const int cpx = gridDim.x >> 3;
  lin = (lin & 7) * cpx + (lin >> 3);
  const int bx = lin % nxg, by = lin / nxg;
  const int brow = by * 256, bcol = bx * BN;
  const int wr = wave >> 2, wc = wave & 3;
  const int arow0 = wr * 128;
  const int bcol0 = wc * (BN/4);

  f32x4 acc[8][NF] = {};

  auto STAGE = [&](int st, int kh) {               // one A-half + one B-half
    const int slot = (2*st + kh) & 3;
    const int koff = st*64 + kh*32;
#pragma unroll
    for (int i = 0; i < 2; ++i) {                  // A: 1024 chunks
      const int qc = i*512 + wave*64 + lane;
      const int row = qc >> 2;
      const int c = (qc & 3) ^ ((row & 3) ^ ((row >> 2) & 3));
      g2l16(A + (size_t)(brow + row)*K + koff + c*8,
            &Ar[slot*8192 + (i*512 + wave*64)*8]);
    }
#pragma unroll
    for (int i = 0; i < BN/128; ++i) {             // B: BN*4 chunks
      const int qc = i*512 + wave*64 + lane;
      const int row = qc >> 2;
      const int c = (qc & 3) ^ ((row & 3) ^ ((row >> 2) & 3));
      g2l16(Bt + (size_t)(bcol + row)*K + koff + c*8,
            &Br[slot*BSLOT + (i*512 + wave*64)*8]);
    }
  };
  auto RDA = [&](int slot, int mh, half8* af) {
#pragma unroll
    for (int i = 0; i < 4; ++i)
      af[i] = *(const half8*)(&Ar[slot*8192 + (arow0 + (mh*4 + i)*16)*32 + laneoff]);
  };
  auto RDB = [&](int slot, half8* bf) {
#pragma unroll
    for (int j = 0; j < NF; ++j)
      bf[j] = *(const half8*)(&Br[slot*BSLOT + (bcol0 + j*16)*32 + laneoff]);
  };

#define MMC(MH) do {                                                          \
    __builtin_amdgcn_s_setprio(1);                                            \
    _Pragma("unroll") for (int i_ = 0; i_ < 4; ++i_)                          \
      _Pragma("unroll") for (int j_ = 0; j_ < NF; ++j_)                       \
        acc[(MH)*4 + i_][j_] = __builtin_amdgcn_mfma_f32_16x16x32_f16(        \
            af[i_], bf[j_], acc[(MH)*4 + i_][j_], 0, 0, 0);                   \
    __builtin_amdgcn_s_setprio(0); } while (0)

  const int ns = K >> 6;                           // >= 3 always here
  STAGE(0, 0); STAGE(0, 1); STAGE(1, 0);
  if constexpr (BN == 256) VMW8; else VMW6;
  SB; BAR;

  half8 af[4], bf[NF];
  for (int s = 0; s < ns - 2; ++s) {
    const int s0 = (2*s) & 3, s1 = s0 + 1;
    // p0
    RDB(s0, bf); RDA(s0, 0, af); STAGE(s + 1, 1);
    SB; BAR; MMC(0); SB; BAR;
    // p1
    RDA(s0, 1, af);
    if constexpr (BN == 256) VMW8; else VMW6;
    SB; BAR; MMC(1); SB; BAR;
    // p2
    RDB(s1, bf); RDA(s1, 0, af); STAGE(s + 2, 0);
    SB; BAR; MMC(0); SB; BAR;
    // p3
    RDA(s1, 1, af);
    if constexpr (BN == 256) VMW8; else VMW6;
    SB; BAR; MMC(1); SB; BAR;
  }
  { // step ns-2: stage only (ns-1,kh1)
    const int s = ns - 2; const int s0 = (2*s) & 3, s1 = s0 + 1;
    RDB(s0, bf); RDA(s0, 0, af); STAGE(s + 1, 1);
    SB; BAR; MMC(0); SB; BAR;
    RDA(s0, 1, af);
    if constexpr (BN == 256) VMW8; else VMW6;
    SB; BAR; MMC(1); SB; BAR;
    RDB(s1, bf); RDA(s1, 0, af);
    SB; BAR; MMC(0); SB; BAR;
    RDA(s1, 1, af);
    if constexpr (BN == 256) VMW4; else VMW3;
    SB; BAR; MMC(1); SB; BAR;
  }
  { // step ns-1: no staging; final drain at p1
    const int s = ns - 1; const int s0 = (2*s) & 3, s1 = s0 + 1;
    RDB(s0, bf); RDA(s0, 0, af);
    SB; BAR; MMC(0); SB; BAR;
    RDA(s0, 1, af);
    VMW0;
    SB; BAR; MMC(1); SB; BAR;
    RDB(s1, bf); RDA(s1, 0, af);
    SB; BAR; MMC(0); SB; BAR;
    RDA(s1, 1, af);
    SB; BAR; MMC(1); SB; BAR;
  }
#undef MMC

  // C/D frag: col = lane&15, row = (lane>>4)*4 + r
#pragma unroll
  for (int a = 0; a < 8; ++a) {
#pragma unroll
    for (int j = 0; j < NF; ++j) {
      const int col = bcol + bcol0 + j*16 + lr;
#pragma unroll
      for (int r = 0; r < 4; ++r) {
        const int row = brow + arow0 + a*16 + lg*4 + r;
        const float v = acc[a][j][r];
        if constexpr (EPI == EPI_QKV) {
          const int sel = col >> 10;            // 0:q 1:k 2:v
          const int cw = col & 1023;
          const int hh = cw >> 6, dd = cw & 63;
          const size_t bhh = (size_t)(row >> 11) * Hn + hh;
          const int t = row & 2047;
          if (sel == 0)      ((_Float16*)outp)[(bhh*Tn + t)*Dn + dd] = (_Float16)v;
          else if (sel == 1) ((_Float16*)out2)[(bhh*Tn + t)*Dn + dd] = (_Float16)v;
          else               ((_Float16*)out3)[(bhh*Dn + dd)*Tn + t] = (_Float16)v;
        } else if constexpr (EPI == EPI_PROJ || EPI == EPI_FF2) {
          ((float*)outp)[(size_t)row * N + col] = v + bias[col] + resid[(size_t)row * N + col];
        } else if constexpr (EPI == EPI_FF1) {
          const float t = v + bias[col];
          ((_Float16*)outp)[(size_t)row * N + col] = (_Float16)(t > 0.f ? t : 0.f);
        }
      }
    }
  }
}

// ---------------- Flash attention (causal), paired q-tiles, KVBLK=64 ----------------
// Swapped-QK^T; exp2-domain in-register softmax with defer-max (T13) and
// diagonal-only masking; P packed via v_cvt_pkrtz; redistribute via shuffles.
__global__ __launch_bounds__(256) void attn_kernel(const _Float16* __restrict__ q,
                                                   const _Float16* __restrict__ k,
                                                   const _Float16* __restrict__ vt,
                                                   _Float16* __restrict__ out) {
  const int pi = blockIdx.x;                 // 0..7
  const int qtA = pi * 128;
  const int qtB = (15 - pi) * 128;
  const int h = blockIdx.y, b = blockIdx.z;
  const int tid = threadIdx.x, wave = tid >> 6, lane = tid & 63;
  const int lr = lane & 15, lg = lane >> 4;
  const size_t bh = (size_t)b * Hn + h;
  const _Float16* qg = q  + bh * (Tn * Dn);
  const _Float16* kg = k  + bh * (Tn * Dn);
  const _Float16* vg = vt + bh * (Dn * Tn);

  __shared__ __align__(16) _Float16 Ks[2][64*64];
  __shared__ __align__(16) _Float16 Vs[2][64*64];

  // Q pre-scale: C^-0.5 * log2(e)  (exp2-domain softmax)
  const _Float16 qsc = (_Float16)(0.03125f * 1.44269504f);
  half8 qfA[2][2], qfB[2][2];
#pragma unroll
  for (int qi = 0; qi < 2; ++qi)
#pragma unroll
    for (int dh = 0; dh < 2; ++dh) {
      half8 a = *(const half8*)(qg + (size_t)(qtA + wave*32 + qi*16 + lr)*Dn + dh*32 + lg*8);
      half8 c = *(const half8*)(qg + (size_t)(qtB + wave*32 + qi*16 + lr)*Dn + dh*32 + lg*8);
#pragma unroll
      for (int j = 0; j < 8; ++j) { a[j] *= qsc; c[j] *= qsc; }
      qfA[qi][dh] = a; qfB[qi][dh] = c;
    }

  f32x4 oaccA[2][4] = {}, oaccB[2][4] = {};
  float mrowA[2] = {-__builtin_inff(), -__builtin_inff()};
  float mrowB[2] = {-__builtin_inff(), -__builtin_inff()};
  float lsumA[2] = {0.f, 0.f}, lsumB[2] = {0.f, 0.f};

  const int ntB = (qtB >> 6) + 2;

  auto STAGE = [&](int bufi, int t) {
    const int kvt = t * 64;
#pragma unroll
    for (int r = 0; r < 2; ++r) {
      const int g0 = r*256 + wave*64;
      const int g  = g0 + lane;
      const int rr = g >> 3;
      const int cs = (g & 7) ^ (rr & 7);
      g2l16(kg + (size_t)(kvt + rr)*Dn + cs*8, &Ks[bufi][g0*8]);
      g2l16(vg + (size_t)rr*Tn + kvt + cs*8,   &Vs[bufi][g0*8]);
    }
  };

  auto COMPUTE = [&](const half8 (&qf)[2][2], f32x4 (&oacc)[2][4],
                     float* mrow, float* lsum, int qb,
                     const _Float16* KS, const _Float16* VS, int kvt) {
    half8 kb[4][2];
#pragma unroll
    for (int f = 0; f < 4; ++f)
#pragma unroll
      for (int dh = 0; dh < 2; ++dh)
        kb[f][dh] = *(const half8*)(KS + (16*f + lr)*64 + (((4*dh + lg) ^ (lr & 7)) * 8));

#pragma unroll
    for (int qi = 0; qi < 2; ++qi) {
      f32x4 sv[4];
#pragma unroll
      for (int f = 0; f < 4; ++f) {
        f32x4 tacc = {0.f, 0.f, 0.f, 0.f};
        tacc = __builtin_amdgcn_mfma_f32_16x16x32_f16(kb[f][0], qf[qi][0], tacc, 0, 0, 0);
        tacc = __builtin_amdgcn_mfma_f32_16x16x32_f16(kb[f][1], qf[qi][1], tacc, 0, 0, 0);
        sv[f] = tacc;
      }
      const int rowbase = qb + wave*32 + qi*16;
      const int qrow = rowbase + lr;
      if (kvt + 63 > rowbase) {          // diagonal tile only (wave-uniform)
#pragma unroll
        for (int f = 0; f < 4; ++f)
#pragma unroll
          for (int r = 0; r < 4; ++r) {
            const int kvv = kvt + 16*f + 4*lg + r;
            sv[f][r] = (kvv > qrow) ? -__builtin_inff() : sv[f][r];
          }
      }
      // row max: tree + 2 shfl
      float t0 = fmaxf(fmaxf(sv[0][0], sv[0][1]), fmaxf(sv[0][2], sv[0][3]));
      float t1 = fmaxf(fmaxf(sv[1][0], sv[1][1]), fmaxf(sv[1][2], sv[1][3]));
      float t2 = fmaxf(fmaxf(sv[2][0], sv[2][1]), fmaxf(sv[2][2], sv[2][3]));
      float t3 = fmaxf(fmaxf(sv[3][0], sv[3][1]), fmaxf(sv[3][2], sv[3][3]));
      float tm = fmaxf(fmaxf(t0, t1), fmaxf(t2, t3));
      tm = fmaxf(tm, __shfl_xor(tm, 16));
      tm = fmaxf(tm, __shfl_xor(tm, 32));
      // defer-max (T13): rescale only when tile max grew past THR (log2 domain)
      if (!__all(tm - mrow[qi] <= 11.5f)) {
        const float mn = fmaxf(mrow[qi], tm);
        const float alpha = exp2f(mrow[qi] - mn);
        mrow[qi] = mn;
        lsum[qi] *= alpha;
        float ab[4];
#pragma unroll
        for (int r = 0; r < 4; ++r) ab[r] = __shfl(alpha, 4*lg + r);
#pragma unroll
        for (int df = 0; df < 4; ++df)
#pragma unroll
          for (int r = 0; r < 4; ++r) oacc[qi][df][r] *= ab[r];
      }
      const float mcur = mrow[qi];
      float ps = 0.f;
      unsigned ph[4][2];
#pragma unroll
      for (int f = 0; f < 4; ++f) {
        const float e0 = exp2f(sv[f][0] - mcur);
        const float e1 = exp2f(sv[f][1] - mcur);
        const float e2 = exp2f(sv[f][2] - mcur);
        const float e3 = exp2f(sv[f][3] - mcur);
        ps += (e0 + e1) + (e2 + e3);
        ph[f][0] = __builtin_bit_cast(unsigned, __builtin_amdgcn_cvt_pkrtz(e0, e1));
        ph[f][1] = __builtin_bit_cast(unsigned, __builtin_amdgcn_cvt_pkrtz(e2, e3));
      }
      ps += __shfl_xor(ps, 16);
      ps += __shfl_xor(ps, 32);
      lsum[qi] += ps;
      // redistribute P -> PV A-frags
      const int s0 = lr + 16*(2*(lg & 1));
      const int s1 = s0 + 16;
      half8 pa[2];
#pragma unroll
      for (int kh = 0; kh < 2; ++kh) {
        u32x4 w = {0u, 0u, 0u, 0u};
#pragma unroll
        for (int fi = 0; fi < 2; ++fi) {
          const unsigned a0 = __shfl(ph[2*kh + fi][0], s0);
          const unsigned a1 = __shfl(ph[2*kh + fi][1], s0);
          const unsigned a2 = __shfl(ph[2*kh + fi][0], s1);
          const unsigned a3 = __shfl(ph[2*kh + fi][1], s1);
          const bool sel = ((lg >> 1) == fi);
          w[0] = sel ? a0 : w[0];
          w[1] = sel ? a1 : w[1];
          w[2] = sel ? a2 : w[2];
          w[3] = sel ? a3 : w[3];
        }
        pa[kh] = __builtin_bit_cast(half8, w);
      }
#pragma unroll
      for (int df = 0; df < 4; ++df) {
        half8 vb0 = *(const half8*)(VS + (16*df + lr)*64 + (((0 + lg) ^ (lr & 7)) * 8));
        half8 vb1 = *(const half8*)(VS + (16*df + lr)*64 + (((4 + lg) ^ (lr & 7)) * 8));
        oacc[qi][df] = __builtin_amdgcn_mfma_f32_16x16x32_f16(pa[0], vb0, oacc[qi][df], 0, 0, 0);
        oacc[qi][df] = __builtin_amdgcn_mfma_f32_16x16x32_f16(pa[1], vb1, oacc[qi][df], 0, 0, 0);
      }
    }
  };

  STAGE(0, 0);
  __syncthreads();

  for (int t = 0; t < ntB; ++t) {
    const int kvt = t * 64;
    if (t + 1 < ntB) STAGE((t + 1) & 1, t + 1);
    const _Float16* KS = Ks[t & 1];
    const _Float16* VS = Vs[t & 1];
    if (kvt <= qtA + wave*32 + 31) COMPUTE(qfA, oaccA, mrowA, lsumA, qtA, KS, VS, kvt);
    if (kvt <= qtB + wave*32 + 31) COMPUTE(qfB, oaccB, mrowB, lsumB, qtB, KS, VS, kvt);
    __syncthreads();
  }

  auto EPI = [&](const f32x4 (&oacc)[2][4], const float* lsum, int qb) {
#pragma unroll
    for (int qi = 0; qi < 2; ++qi) {
      const float linv = 1.0f / lsum[qi];
      float lb[4];
#pragma unroll
      for (int r = 0; r < 4; ++r) lb[r] = __shfl(linv, 4*lg + r);
#pragma unroll
      for (int df = 0; df < 4; ++df)
#pragma unroll
        for (int r = 0; r < 4; ++r) {
          const int row = qb + wave*32 + qi*16 + 4*lg + r;
          const int col = h*Dn + df*16 + lr;
          out[((size_t)b*Tn + row)*Cn + col] = (_Float16)(oacc[qi][df][r] * lb[r]);
        }
    }
  };
  EPI(oaccA, lsumA, qtA);
  EPI(oaccB, lsumB, qtB);
}

// ---------------- host launch ----------------
extern "C" void kernel_launch(void* const* d_in, const int* in_sizes, int n_in,
                              void* d_out, int out_size, void* d_ws, size_t ws_size,
                              hipStream_t stream) {
  const float* x      = (const float*)d_in[0];
  const float* wq     = (const float*)d_in[1];
  const float* wk     = (const float*)d_in[2];
  const float* wv     = (const float*)d_in[3];
  const float* w_proj = (const float*)d_in[4];
  const float* b_proj = (const float*)d_in[5];
  const float* w_ff1  = (const float*)d_in[6];
  const float* b_ff1  = (const float*)d_in[7];
  const float* w_ff2  = (const float*)d_in[8];
  const float* b_ff2  = (const float*)d_in[9];
  const float* ln1s   = (const float*)d_in[10];
  const float* ln1b   = (const float*)d_in[11];
  const float* ln2s   = (const float*)d_in[12];
  const float* ln2b   = (const float*)d_in[13];
  float* outp = (float*)d_out;

  char* ws = (char*)d_ws;
  constexpr size_t MB = (size_t)1 << 20;
  _Float16* Wq_t  = (_Float16*)(ws + 0*MB);    // [1024][1024]; Wq/Wk/Wv contiguous =
  _Float16* Wk_t  = (_Float16*)(ws + 2*MB);    //   fused QKV B^T [3072][1024]
  _Float16* Wv_t  = (_Float16*)(ws + 4*MB);
  _Float16* Wp_t  = (_Float16*)(ws + 6*MB);
  _Float16* Wf1_t = (_Float16*)(ws + 8*MB);    // [4096][1024]
  _Float16* Wf2_t = (_Float16*)(ws + 16*MB);   // [1024][4096]
  _Float16* xn    = (_Float16*)(ws + 24*MB);   // [8192][1024]; reused as attn_out
  _Float16* attn_o= (_Float16*)(ws + 24*MB);
  _Float16* qbuf  = (_Float16*)(ws + 40*MB);   // [b][h][t][d]
  _Float16* kbuf  = (_Float16*)(ws + 56*MB);
  _Float16* vtbuf = (_Float16*)(ws + 72*MB);   // [b][h][d][t]
  _Float16* hbuf  = (_Float16*)(ws + 40*MB);   // [8192][4096]; overlays q/k/vt (dead by FF1)
  float*    x2    = (float*)   (ws + 104*MB);  // [8192][1024] f32
  _Float16* xn2   = (_Float16*)(ws + 136*MB);  // [8192][1024]

  dim3 tb(32, 8);
  transpose_f32_f16<<<dim3(2, 32, 16), tb, 0, stream>>>(wq, Wq_t, 1024, 64);
  transpose_f32_f16<<<dim3(2, 32, 16), tb, 0, stream>>>(wk, Wk_t, 1024, 64);
  transpose_f32_f16<<<dim3(2, 32, 16), tb, 0, stream>>>(wv, Wv_t, 1024, 64);
  transpose_f32_f16<<<dim3(32, 32, 1), tb, 0, stream>>>(w_proj, Wp_t, 1024, 1024);
  transpose_f32_f16<<<dim3(128, 32, 1), tb, 0, stream>>>(w_ff1, Wf1_t, 1024, 4096);
  transpose_f32_f16<<<dim3(32, 128, 1), tb, 0, stream>>>(w_ff2, Wf2_t, 4096, 1024);

  ln_row<<<Mr, 256, 0, stream>>>(x, ln1s, ln1b, xn);

  // fused QKV: N=3072, BN=128 -> 24x32 = 768 wg (3 exact rounds at 1 wg/CU)
  gemm8p<128, EPI_QKV><<<dim3(768), 512, 0, stream>>>(xn, Wq_t, qbuf, kbuf, vtbuf,
                                                      nullptr, nullptr, Mr, 3*Cn, Cn, 24);

  attn_kernel<<<dim3(8, Hn, Bn), 256, 0, stream>>>(qbuf, kbuf, vtbuf, attn_o);

  // proj + residual: N=1024, BN=128 -> 8x32 = 256 wg (1 round)
  gemm8p<128, EPI_PROJ><<<dim3(256), 512, 0, stream>>>(attn_o, Wp_t, x2, nullptr, nullptr,
                                                       b_proj, x, Mr, Cn, Cn, 8);

  ln_row<<<Mr, 256, 0, stream>>>(x2, ln2s, ln2b, xn2);

  // FF1: N=4096, BN=256 -> 16x32 = 512 wg (2 exact rounds)
  gemm8p<256, EPI_FF1><<<dim3(512), 512, 0, stream>>>(xn2, Wf1_t, hbuf, nullptr, nullptr,
                                                      b_ff1, nullptr, Mr, 4*Cn, Cn, 16);
  // FF2: N=1024, K=4096, BN=128 -> 8x32 = 256 wg (1 round)
  gemm8p<128, EPI_FF2><<<dim3(256), 512, 0, stream>>>(hbuf, Wf2_t, outp, nullptr, nullptr,
                                                      b_ff2, x2, Mr, Cn, 4*Cn, 8);
}

// Round 10
// 612.767 us; speedup vs baseline: 1.0065x; 1.0065x over previous
//
#include <hip/hip_runtime.h>

// ---------------- constants ----------------
#define Bn 4
#define Tn 2048
#define Cn 1024
#define Hn 16
#define Dn 64
#define Mr (Bn*Tn)          // 8192 rows

typedef _Float16 half8 __attribute__((ext_vector_type(8)));
typedef _Float16 half4v __attribute__((ext_vector_type(4)));
typedef _Float16 half2v __attribute__((ext_vector_type(2)));
typedef float f32x4 __attribute__((ext_vector_type(4)));
typedef unsigned u32x4 __attribute__((ext_vector_type(4)));

__device__ __forceinline__ void g2l16(const void* g, void* l) {
  __builtin_amdgcn_global_load_lds((__attribute__((address_space(1))) void*)g,
                                   (__attribute__((address_space(3))) void*)l, 16, 0, 0);
}

#define SB  __builtin_amdgcn_sched_barrier(0)
#define BAR __builtin_amdgcn_s_barrier()
#define VMW8 asm volatile("s_waitcnt vmcnt(8)" ::: "memory")
#define VMW6 asm volatile("s_waitcnt vmcnt(6)" ::: "memory")
#define VMW4 asm volatile("s_waitcnt vmcnt(4)" ::: "memory")
#define VMW3 asm volatile("s_waitcnt vmcnt(3)" ::: "memory")
#define VMW0 asm volatile("s_waitcnt vmcnt(0)" ::: "memory")

// ---------------- transpose f32 -> f16 (B^T weight prep) ----------------
__global__ __launch_bounds__(256) void transpose_f32_f16(const float* __restrict__ in,
                                                         _Float16* __restrict__ out,
                                                         int R, int C) {
  __shared__ float tile[32][33];
  const size_t zoff = (size_t)blockIdx.z * R * C;
  in += zoff; out += zoff;
  const int c0 = blockIdx.x * 32, r0 = blockIdx.y * 32;
  const int tx = threadIdx.x, ty = threadIdx.y;
#pragma unroll
  for (int i = 0; i < 4; ++i)
    tile[ty + i*8][tx] = in[(size_t)(r0 + ty + i*8) * C + c0 + tx];
  __syncthreads();
#pragma unroll
  for (int i = 0; i < 4; ++i)
    out[(size_t)(c0 + ty + i*8) * R + r0 + tx] = (_Float16)tile[tx][ty + i*8];
}

// ---------------- LayerNorm row kernel: f32 in -> f16 out ----------------
__global__ __launch_bounds__(256) void ln_row(const float* __restrict__ x,
                                              const float* __restrict__ g,
                                              const float* __restrict__ bta,
                                              _Float16* __restrict__ out) {
  const int row = blockIdx.x;
  const float4 v = ((const float4*)(x + (size_t)row * Cn))[threadIdx.x];
  float s  = v.x + v.y + v.z + v.w;
  float ss = v.x*v.x + v.y*v.y + v.z*v.z + v.w*v.w;
#pragma unroll
  for (int m = 1; m < 64; m <<= 1) { s += __shfl_xor(s, m); ss += __shfl_xor(ss, m); }
  __shared__ float red[8];
  const int wave = threadIdx.x >> 6, lane = threadIdx.x & 63;
  if (lane == 0) { red[wave] = s; red[4 + wave] = ss; }
  __syncthreads();
  s  = red[0] + red[1] + red[2] + red[3];
  ss = red[4] + red[5] + red[6] + red[7];
  const float mean = s * (1.0f/Cn);
  const float var  = ss * (1.0f/Cn) - mean*mean;
  const float rstd = rsqrtf(var + 1e-6f);
  const int c = threadIdx.x * 4;
  const float4 gg = ((const float4*)g)[threadIdx.x];
  const float4 bb = ((const float4*)bta)[threadIdx.x];
  half4v o;
  o[0] = (_Float16)((v.x - mean) * rstd * gg.x + bb.x);
  o[1] = (_Float16)((v.y - mean) * rstd * gg.y + bb.y);
  o[2] = (_Float16)((v.z - mean) * rstd * gg.z + bb.z);
  o[3] = (_Float16)((v.w - mean) * rstd * gg.w + bb.w);
  *((half4v*)(out + (size_t)row * Cn + c)) = o;
}

// ---------------- GEMM v3: 8-phase schedule, BM=256, BK=64, 8 waves ----------------
enum { EPI_QKV = 0, EPI_PROJ = 2, EPI_FF1 = 3, EPI_FF2 = 4 };

template<int BN, int EPI>
__global__ __launch_bounds__(512, 2) void gemm8p(const _Float16* __restrict__ A,
                                                 const _Float16* __restrict__ Bt,
                                                 void* __restrict__ outp,
                                                 void* __restrict__ out2,   // QKV: k
                                                 void* __restrict__ out3,   // QKV: vt
                                                 const float* __restrict__ bias,
                                                 const float* __restrict__ resid,
                                                 int M, int N, int K, int nxg) {
  constexpr int NF = BN/64;               // N-frags per wave (4 or 2)
  constexpr int BSLOT = BN*32;            // f16 per B slot
  __shared__ __align__(16) _Float16 Ar[4*256*32];
  __shared__ __align__(16) _Float16 Br[4*BSLOT];

  const int tid = threadIdx.x, wave = tid >> 6, lane = tid & 63;
  const int lr = lane & 15, lg = lane >> 4;
  const int sL = (lr & 3) ^ ((lr >> 2) & 3);
  const int laneoff = lr*32 + ((lg ^ sL) * 8);     // f16 offset within a slot

  // bijective XCD swizzle (gridDim.x % 8 == 0 for all our launches)
  int lin = blockIdx.x;
  const int cpx = gridDim.x >> 3;
  lin = (lin & 7) * cpx + (lin >> 3);
  const int bx = lin % nxg, by = lin / nxg;
  const int brow = by * 256, bcol = bx * BN;
  const int wr = wave >> 2, wc = wave & 3;
  const int arow0 = wr * 128;
  const int bcol0 = wc * (BN/4);

  f32x4 acc[8][NF] = {};

  auto STAGE = [&](int st, int kh) {               // one A-half + one B-half
    const int slot = (2*st + kh) & 3;
    const int koff = st*64 + kh*32;
#pragma unroll
    for (int i = 0; i < 2; ++i) {                  // A: 1024 chunks
      const int qc = i*512 + wave*64 + lane;
      const int row = qc >> 2;
      const int c = (qc & 3) ^ ((row & 3) ^ ((row >> 2) & 3));
      g2l16(A + (size_t)(brow + row)*K + koff + c*8,
            &Ar[slot*8192 + (i*512 + wave*64)*8]);
    }
#pragma unroll
    for (int i = 0; i < BN/128; ++i) {             // B: BN*4 chunks
      const int qc = i*512 + wave*64 + lane;
      const int row = qc >> 2;
      const int c = (qc & 3) ^ ((row & 3) ^ ((row >> 2) & 3));
      g2l16(Bt + (size_t)(bcol + row)*K + koff + c*8,
            &Br[slot*BSLOT + (i*512 + wave*64)*8]);
    }
  };
  auto RDA = [&](int slot, int mh, half8* af) {
#pragma unroll
    for (int i = 0; i < 4; ++i)
      af[i] = *(const half8*)(&Ar[slot*8192 + (arow0 + (mh*4 + i)*16)*32 + laneoff]);
  };
  auto RDB = [&](int slot, half8* bf) {
#pragma unroll
    for (int j = 0; j < NF; ++j)
      bf[j] = *(const half8*)(&Br[slot*BSLOT + (bcol0 + j*16)*32 + laneoff]);
  };

#define MMC(MH) do {                                                          \
    __builtin_amdgcn_s_setprio(1);                                            \
    _Pragma("unroll") for (int i_ = 0; i_ < 4; ++i_)                          \
      _Pragma("unroll") for (int j_ = 0; j_ < NF; ++j_)                       \
        acc[(MH)*4 + i_][j_] = __builtin_amdgcn_mfma_f32_16x16x32_f16(        \
            af[i_], bf[j_], acc[(MH)*4 + i_][j_], 0, 0, 0);                   \
    __builtin_amdgcn_s_setprio(0); } while (0)

  const int ns = K >> 6;                           // >= 3 always here
  STAGE(0, 0); STAGE(0, 1); STAGE(1, 0);
  if constexpr (BN == 256) VMW8; else VMW6;
  SB; BAR;

  half8 af[4], bf[NF];
  for (int s = 0; s < ns - 2; ++s) {
    const int s0 = (2*s) & 3, s1 = s0 + 1;
    // p0
    RDB(s0, bf); RDA(s0, 0, af); STAGE(s + 1, 1);
    SB; BAR; MMC(0); SB; BAR;
    // p1
    RDA(s0, 1, af);
    if constexpr (BN == 256) VMW8; else VMW6;
    SB; BAR; MMC(1); SB; BAR;
    // p2
    RDB(s1, bf); RDA(s1, 0, af); STAGE(s + 2, 0);
    SB; BAR; MMC(0); SB; BAR;
    // p3
    RDA(s1, 1, af);
    if constexpr (BN == 256) VMW8; else VMW6;
    SB; BAR; MMC(1); SB; BAR;
  }
  { // step ns-2: stage only (ns-1,kh1)
    const int s = ns - 2; const int s0 = (2*s) & 3, s1 = s0 + 1;
    RDB(s0, bf); RDA(s0, 0, af); STAGE(s + 1, 1);
    SB; BAR; MMC(0); SB; BAR;
    RDA(s0, 1, af);
    if constexpr (BN == 256) VMW8; else VMW6;
    SB; BAR; MMC(1); SB; BAR;
    RDB(s1, bf); RDA(s1, 0, af);
    SB; BAR; MMC(0); SB; BAR;
    RDA(s1, 1, af);
    if constexpr (BN == 256) VMW4; else VMW3;
    SB; BAR; MMC(1); SB; BAR;
  }
  { // step ns-1: no staging; final drain at p1
    const int s = ns - 1; const int s0 = (2*s) & 3, s1 = s0 + 1;
    RDB(s0, bf); RDA(s0, 0, af);
    SB; BAR; MMC(0); SB; BAR;
    RDA(s0, 1, af);
    VMW0;
    SB; BAR; MMC(1); SB; BAR;
    RDB(s1, bf); RDA(s1, 0, af);
    SB; BAR; MMC(0); SB; BAR;
    RDA(s1, 1, af);
    SB; BAR; MMC(1); SB; BAR;
  }
#undef MMC

  // C/D frag: col = lane&15, row = (lane>>4)*4 + r
#pragma unroll
  for (int a = 0; a < 8; ++a) {
#pragma unroll
    for (int j = 0; j < NF; ++j) {
      const int col = bcol + bcol0 + j*16 + lr;
#pragma unroll
      for (int r = 0; r < 4; ++r) {
        const int row = brow + arow0 + a*16 + lg*4 + r;
        const float v = acc[a][j][r];
        if constexpr (EPI == EPI_QKV) {
          const int sel = col >> 10;            // 0:q 1:k 2:v
          const int cw = col & 1023;
          const int hh = cw >> 6, dd = cw & 63;
          const size_t bhh = (size_t)(row >> 11) * Hn + hh;
          const int t = row & 2047;
          if (sel == 0)      ((_Float16*)outp)[(bhh*Tn + t)*Dn + dd] = (_Float16)v;
          else if (sel == 1) ((_Float16*)out2)[(bhh*Tn + t)*Dn + dd] = (_Float16)v;
          else               ((_Float16*)out3)[(bhh*Dn + dd)*Tn + t] = (_Float16)v;
        } else if constexpr (EPI == EPI_PROJ || EPI == EPI_FF2) {
          ((float*)outp)[(size_t)row * N + col] = v + bias[col] + resid[(size_t)row * N + col];
        } else if constexpr (EPI == EPI_FF1) {
          const float t = v + bias[col];
          ((_Float16*)outp)[(size_t)row * N + col] = (_Float16)(t > 0.f ? t : 0.f);
        }
      }
    }
  }
}

// ---------------- Flash attention (causal), paired q-tiles, KVBLK=64 ----------------
// Round-7 straight-line control flow (always mask, always rescale) with
// branch-free instruction diet: exp2-domain softmax + v_cvt_pkrtz P packing.
__global__ __launch_bounds__(256) void attn_kernel(const _Float16* __restrict__ q,
                                                   const _Float16* __restrict__ k,
                                                   const _Float16* __restrict__ vt,
                                                   _Float16* __restrict__ out) {
  const int pi = blockIdx.x;                 // 0..7
  const int qtA = pi * 128;
  const int qtB = (15 - pi) * 128;
  const int h = blockIdx.y, b = blockIdx.z;
  const int tid = threadIdx.x, wave = tid >> 6, lane = tid & 63;
  const int lr = lane & 15, lg = lane >> 4;
  const size_t bh = (size_t)b * Hn + h;
  const _Float16* qg = q  + bh * (Tn * Dn);
  const _Float16* kg = k  + bh * (Tn * Dn);
  const _Float16* vg = vt + bh * (Dn * Tn);

  __shared__ __align__(16) _Float16 Ks[2][64*64];
  __shared__ __align__(16) _Float16 Vs[2][64*64];

  // Q pre-scale: C^-0.5 * log2(e)  (exp2-domain softmax)
  const _Float16 qsc = (_Float16)(0.03125f * 1.44269504f);
  half8 qfA[2][2], qfB[2][2];
#pragma unroll
  for (int qi = 0; qi < 2; ++qi)
#pragma unroll
    for (int dh = 0; dh < 2; ++dh) {
      half8 a = *(const half8*)(qg + (size_t)(qtA + wave*32 + qi*16 + lr)*Dn + dh*32 + lg*8);
      half8 c = *(const half8*)(qg + (size_t)(qtB + wave*32 + qi*16 + lr)*Dn + dh*32 + lg*8);
#pragma unroll
      for (int j = 0; j < 8; ++j) { a[j] *= qsc; c[j] *= qsc; }
      qfA[qi][dh] = a; qfB[qi][dh] = c;
    }

  f32x4 oaccA[2][4] = {}, oaccB[2][4] = {};
  float mrowA[2] = {-__builtin_inff(), -__builtin_inff()};
  float mrowB[2] = {-__builtin_inff(), -__builtin_inff()};
  float lsumA[2] = {0.f, 0.f}, lsumB[2] = {0.f, 0.f};

  const int ntB = (qtB >> 6) + 2;

  auto STAGE = [&](int bufi, int t) {
    const int kvt = t * 64;
#pragma unroll
    for (int r = 0; r < 2; ++r) {
      const int g0 = r*256 + wave*64;
      const int g  = g0 + lane;
      const int rr = g >> 3;
      const int cs = (g & 7) ^ (rr & 7);
      g2l16(kg + (size_t)(kvt + rr)*Dn + cs*8, &Ks[bufi][g0*8]);
      g2l16(vg + (size_t)rr*Tn + kvt + cs*8,   &Vs[bufi][g0*8]);
    }
  };

  auto COMPUTE = [&](const half8 (&qf)[2][2], f32x4 (&oacc)[2][4],
                     float* mrow, float* lsum, int qb,
                     const _Float16* KS, const _Float16* VS, int kvt) {
    half8 kb[4][2];
#pragma unroll
    for (int f = 0; f < 4; ++f)
#pragma unroll
      for (int dh = 0; dh < 2; ++dh)
        kb[f][dh] = *(const half8*)(KS + (16*f + lr)*64 + (((4*dh + lg) ^ (lr & 7)) * 8));

#pragma unroll
    for (int qi = 0; qi < 2; ++qi) {
      f32x4 sv[4];
#pragma unroll
      for (int f = 0; f < 4; ++f) {
        f32x4 tacc = {0.f, 0.f, 0.f, 0.f};
        tacc = __builtin_amdgcn_mfma_f32_16x16x32_f16(kb[f][0], qf[qi][0], tacc, 0, 0, 0);
        tacc = __builtin_amdgcn_mfma_f32_16x16x32_f16(kb[f][1], qf[qi][1], tacc, 0, 0, 0);
        sv[f] = tacc;
      }
      const int qrow = qb + wave*32 + qi*16 + lr;
#pragma unroll
      for (int f = 0; f < 4; ++f)
#pragma unroll
        for (int r = 0; r < 4; ++r) {
          const int kvv = kvt + 16*f + 4*lg + r;
          sv[f][r] = (kvv > qrow) ? -__builtin_inff() : sv[f][r];
        }
      // row max: tree + 2 shfl
      float t0 = fmaxf(fmaxf(sv[0][0], sv[0][1]), fmaxf(sv[0][2], sv[0][3]));
      float t1 = fmaxf(fmaxf(sv[1][0], sv[1][1]), fmaxf(sv[1][2], sv[1][3]));
      float t2 = fmaxf(fmaxf(sv[2][0], sv[2][1]), fmaxf(sv[2][2], sv[2][3]));
      float t3 = fmaxf(fmaxf(sv[3][0], sv[3][1]), fmaxf(sv[3][2], sv[3][3]));
      float tm = fmaxf(fmaxf(t0, t1), fmaxf(t2, t3));
      tm = fmaxf(tm, __shfl_xor(tm, 16));
      tm = fmaxf(tm, __shfl_xor(tm, 32));
      const float mn = fmaxf(mrow[qi], tm);
      const float alpha = exp2f(mrow[qi] - mn);
      mrow[qi] = mn;
      float ps = 0.f;
      unsigned ph[4][2];
#pragma unroll
      for (int f = 0; f < 4; ++f) {
        const float e0 = exp2f(sv[f][0] - mn);
        const float e1 = exp2f(sv[f][1] - mn);
        const float e2 = exp2f(sv[f][2] - mn);
        const float e3 = exp2f(sv[f][3] - mn);
        ps += (e0 + e1) + (e2 + e3);
        ph[f][0] = __builtin_bit_cast(unsigned, __builtin_amdgcn_cvt_pkrtz(e0, e1));
        ph[f][1] = __builtin_bit_cast(unsigned, __builtin_amdgcn_cvt_pkrtz(e2, e3));
      }
      ps += __shfl_xor(ps, 16);
      ps += __shfl_xor(ps, 32);
      lsum[qi] = lsum[qi] * alpha + ps;
      // rescale O rows (alpha lives at lane q_local = 4lg+r)
      float ab[4];
#pragma unroll
      for (int r = 0; r < 4; ++r) ab[r] = __shfl(alpha, 4*lg + r);
#pragma unroll
      for (int df = 0; df < 4; ++df)
#pragma unroll
        for (int r = 0; r < 4; ++r) oacc[qi][df][r] *= ab[r];
      // redistribute P -> PV A-frags
      const int s0 = lr + 16*(2*(lg & 1));
      const int s1 = s0 + 16;
      half8 pa[2];
#pragma unroll
      for (int kh = 0; kh < 2; ++kh) {
        u32x4 w = {0u, 0u, 0u, 0u};
#pragma unroll
        for (int fi = 0; fi < 2; ++fi) {
          const unsigned a0 = __shfl(ph[2*kh + fi][0], s0);
          const unsigned a1 = __shfl(ph[2*kh + fi][1], s0);
          const unsigned a2 = __shfl(ph[2*kh + fi][0], s1);
          const unsigned a3 = __shfl(ph[2*kh + fi][1], s1);
          const bool sel = ((lg >> 1) == fi);
          w[0] = sel ? a0 : w[0];
          w[1] = sel ? a1 : w[1];
          w[2] = sel ? a2 : w[2];
          w[3] = sel ? a3 : w[3];
        }
        pa[kh] = __builtin_bit_cast(half8, w);
      }
#pragma unroll
      for (int df = 0; df < 4; ++df) {
        half8 vb0 = *(const half8*)(VS + (16*df + lr)*64 + (((0 + lg) ^ (lr & 7)) * 8));
        half8 vb1 = *(const half8*)(VS + (16*df + lr)*64 + (((4 + lg) ^ (lr & 7)) * 8));
        oacc[qi][df] = __builtin_amdgcn_mfma_f32_16x16x32_f16(pa[0], vb0, oacc[qi][df], 0, 0, 0);
        oacc[qi][df] = __builtin_amdgcn_mfma_f32_16x16x32_f16(pa[1], vb1, oacc[qi][df], 0, 0, 0);
      }
    }
  };

  STAGE(0, 0);
  __syncthreads();

  for (int t = 0; t < ntB; ++t) {
    const int kvt = t * 64;
    if (t + 1 < ntB) STAGE((t + 1) & 1, t + 1);
    const _Float16* KS = Ks[t & 1];
    const _Float16* VS = Vs[t & 1];
    if (kvt <= qtA + wave*32 + 31) COMPUTE(qfA, oaccA, mrowA, lsumA, qtA, KS, VS, kvt);
    if (kvt <= qtB + wave*32 + 31) COMPUTE(qfB, oaccB, mrowB, lsumB, qtB, KS, VS, kvt);
    __syncthreads();
  }

  auto EPI = [&](const f32x4 (&oacc)[2][4], const float* lsum, int qb) {
#pragma unroll
    for (int qi = 0; qi < 2; ++qi) {
      const float linv = 1.0f / lsum[qi];
      float lb[4];
#pragma unroll
      for (int r = 0; r < 4; ++r) lb[r] = __shfl(linv, 4*lg + r);
#pragma unroll
      for (int df = 0; df < 4; ++df)
#pragma unroll
        for (int r = 0; r < 4; ++r) {
          const int row = qb + wave*32 + qi*16 + 4*lg + r;
          const int col = h*Dn + df*16 + lr;
          out[((size_t)b*Tn + row)*Cn + col] = (_Float16)(oacc[qi][df][r] * lb[r]);
        }
    }
  };
  EPI(oaccA, lsumA, qtA);
  EPI(oaccB, lsumB, qtB);
}

// ---------------- host launch ----------------
extern "C" void kernel_launch(void* const* d_in, const int* in_sizes, int n_in,
                              void* d_out, int out_size, void* d_ws, size_t ws_size,
                              hipStream_t stream) {
  const float* x      = (const float*)d_in[0];
  const float* wq     = (const float*)d_in[1];
  const float* wk     = (const float*)d_in[2];
  const float* wv     = (const float*)d_in[3];
  const float* w_proj = (const float*)d_in[4];
  const float* b_proj = (const float*)d_in[5];
  const float* w_ff1  = (const float*)d_in[6];
  const float* b_ff1  = (const float*)d_in[7];
  const float* w_ff2  = (const float*)d_in[8];
  const float* b_ff2  = (const float*)d_in[9];
  const float* ln1s   = (const float*)d_in[10];
  const float* ln1b   = (const float*)d_in[11];
  const float* ln2s   = (const float*)d_in[12];
  const float* ln2b   = (const float*)d_in[13];
  float* outp = (float*)d_out;

  char* ws = (char*)d_ws;
  constexpr size_t MB = (size_t)1 << 20;
  _Float16* Wq_t  = (_Float16*)(ws + 0*MB);    // [1024][1024]; Wq/Wk/Wv contiguous =
  _Float16* Wk_t  = (_Float16*)(ws + 2*MB);    //   fused QKV B^T [3072][1024]
  _Float16* Wv_t  = (_Float16*)(ws + 4*MB);
  _Float16* Wp_t  = (_Float16*)(ws + 6*MB);
  _Float16* Wf1_t = (_Float16*)(ws + 8*MB);    // [4096][1024]
  _Float16* Wf2_t = (_Float16*)(ws + 16*MB);   // [1024][4096]
  _Float16* xn    = (_Float16*)(ws + 24*MB);   // [8192][1024]; reused as attn_out
  _Float16* attn_o= (_Float16*)(ws + 24*MB);
  _Float16* qbuf  = (_Float16*)(ws + 40*MB);   // [b][h][t][d]
  _Float16* kbuf  = (_Float16*)(ws + 56*MB);
  _Float16* vtbuf = (_Float16*)(ws + 72*MB);   // [b][h][d][t]
  _Float16* hbuf  = (_Float16*)(ws + 40*MB);   // [8192][4096]; overlays q/k/vt (dead by FF1)
  float*    x2    = (float*)   (ws + 104*MB);  // [8192][1024] f32
  _Float16* xn2   = (_Float16*)(ws + 136*MB);  // [8192][1024]

  dim3 tb(32, 8);
  transpose_f32_f16<<<dim3(2, 32, 16), tb, 0, stream>>>(wq, Wq_t, 1024, 64);
  transpose_f32_f16<<<dim3(2, 32, 16), tb, 0, stream>>>(wk, Wk_t, 1024, 64);
  transpose_f32_f16<<<dim3(2, 32, 16), tb, 0, stream>>>(wv, Wv_t, 1024, 64);
  transpose_f32_f16<<<dim3(32, 32, 1), tb, 0, stream>>>(w_proj, Wp_t, 1024, 1024);
  transpose_f32_f16<<<dim3(128, 32, 1), tb, 0, stream>>>(w_ff1, Wf1_t, 1024, 4096);
  transpose_f32_f16<<<dim3(32, 128, 1), tb, 0, stream>>>(w_ff2, Wf2_t, 4096, 1024);

  ln_row<<<Mr, 256, 0, stream>>>(x, ln1s, ln1b, xn);

  // fused QKV: N=3072, BN=128 -> 24x32 = 768 wg (3 exact rounds at 1 wg/CU)
  gemm8p<128, EPI_QKV><<<dim3(768), 512, 0, stream>>>(xn, Wq_t, qbuf, kbuf, vtbuf,
                                                      nullptr, nullptr, Mr, 3*Cn, Cn, 24);

  attn_kernel<<<dim3(8, Hn, Bn), 256, 0, stream>>>(qbuf, kbuf, vtbuf, attn_o);

  // proj + residual: N=1024, BN=128 -> 8x32 = 256 wg (1 round)
  gemm8p<128, EPI_PROJ><<<dim3(256), 512, 0, stream>>>(attn_o, Wp_t, x2, nullptr, nullptr,
                                                       b_proj, x, Mr, Cn, Cn, 8);

  ln_row<<<Mr, 256, 0, stream>>>(x2, ln2s, ln2b, xn2);

  // FF1: N=4096, BN=256 -> 16x32 = 512 wg (2 exact rounds)
  gemm8p<256, EPI_FF1><<<dim3(512), 512, 0, stream>>>(xn2, Wf1_t, hbuf, nullptr, nullptr,
                                                      b_ff1, nullptr, Mr, 4*Cn, Cn, 16);
  // FF2: N=1024, K=4096, BN=128 -> 8x32 = 256 wg (1 round)
  gemm8p<128, EPI_FF2><<<dim3(256), 512, 0, stream>>>(hbuf, Wf2_t, outp, nullptr, nullptr,
                                                      b_ff2, x2, Mr, Cn, 4*Cn, 8);
}